// Round 19
// baseline (209.199 us; speedup 1.0000x reference)
//
#include <hip/hip_runtime.h>
#include <stdint.h>
#include <math.h>

#pragma clang fp contract(off)

// ===========================================================================
// Threefry-2x32 (20 rounds) — constexpr so the wave-uniform key tree folds.
// Stream (CONFIRMED r11-r13): jax partitionable; split row i = tf(key,(0,i));
// 32-bit random_bits = x^y; root key(1) = (0,1); f32 draws.
// Gamma chain (CONFIRMED r13): ek=split(gkey)[i]; k=split2(ek)[0];
// loop{nk,xk,Uk=split3(k); sub=split2(xk)[1]}; MT c=(1/3)rsqrt(d).
// r18: (a) single-exp Wood (exp_x(0)==1.0f exactly -> select), (b) prep_keys
// precomputes first-proposal chain keys into zo[1..4] (4 tf/site saved).
// ===========================================================================
struct U2 { uint32_t x, y; };

__host__ __device__ constexpr U2 tf(uint32_t k0, uint32_t k1, uint32_t x0, uint32_t x1) {
  uint32_t k2 = k0 ^ k1 ^ 0x1BD11BDAu;
#define TF_R(r) { x0 += x1; x1 = (x1 << (r)) | (x1 >> (32 - (r))); x1 ^= x0; }
  x0 += k0; x1 += k1;
  TF_R(13) TF_R(15) TF_R(26) TF_R(6)
  x0 += k1; x1 += k2 + 1u;
  TF_R(17) TF_R(29) TF_R(16) TF_R(24)
  x0 += k2; x1 += k0 + 2u;
  TF_R(13) TF_R(15) TF_R(26) TF_R(6)
  x0 += k0; x1 += k1 + 3u;
  TF_R(17) TF_R(29) TF_R(16) TF_R(24)
  x0 += k1; x1 += k2 + 4u;
  TF_R(13) TF_R(15) TF_R(26) TF_R(6)
  x0 += k2; x1 += k0 + 5u;
#undef TF_R
  return U2{x0, x1};
}

__device__ constexpr U2 T0 = tf(0u, 1u, 0u, 0u);
__device__ constexpr U2 T1 = tf(0u, 1u, 0u, 1u);
__device__ constexpr U2 T2 = tf(0u, 1u, 0u, 2u);
__device__ constexpr U2 KA = tf(T0.x, T0.y, 0u, 0u);
__device__ constexpr U2 KB = tf(T0.x, T0.y, 0u, 1u);

__device__ __forceinline__ U2 srow(U2 k, uint32_t i) { return tf(k.x, k.y, 0u, i); }
__device__ __forceinline__ uint32_t rb(U2 k, uint32_t i) {
  U2 r = tf(k.x, k.y, 0u, i); return r.x ^ r.y;
}

__device__ __forceinline__ float u01f(uint32_t b) {
  return __uint_as_float((b >> 9) | 0x3F800000u) - 1.0f;
}

// ===========================================================================
// f32 XLA Cephes math (bit-exact with reference; do not alter)
// ===========================================================================
__device__ float log_x(float a) {
  if (a == 0.0f) return -__builtin_inff();
  if (a < 0.0f) return __builtin_nanf("");
  if (__builtin_isinf(a)) return a;
  uint32_t bits = __float_as_uint(a);
  int e = (int)(bits >> 23) - 126;
  float m = __uint_as_float((bits & 0x007FFFFFu) | 0x3F000000u);
  if (m < 0.70710678118654752440f) { e -= 1; m = m + m - 1.0f; }
  else                             { m = m - 1.0f; }
  float z = m * m;
  float y = fmaf(7.0376836292E-2f, m, -1.1514610310E-1f);
  y = fmaf(y, m,  1.1676998740E-1f);
  y = fmaf(y, m, -1.2420140846E-1f);
  y = fmaf(y, m,  1.4249322787E-1f);
  y = fmaf(y, m, -1.6668057665E-1f);
  y = fmaf(y, m,  2.0000714765E-1f);
  y = fmaf(y, m, -2.4999993993E-1f);
  y = fmaf(y, m,  3.3333331174E-1f);
  y = y * m; y = y * z;
  y = fmaf((float)e, -2.12194440e-4f, y);
  y = fmaf(z, -0.5f, y);
  float r = m + y;
  r = fmaf((float)e, 0.693359375f, r);
  return r;
}

__device__ float exp_x(float a) {
  float x = fminf(a, 88.3762626647950f);
  x = fmaxf(x, -88.3762626647949f);
  float fx = floorf(fmaf(x, 1.44269504088896341f, 0.5f));
  x = x - fx * 0.693359375f;
  x = x - fx * (-2.12194440e-4f);
  float z = x * x;
  float y = fmaf(1.9875691500E-4f, x, 1.3981999507E-3f);
  y = fmaf(y, x, 8.3334519073E-3f);
  y = fmaf(y, x, 4.1665795894E-2f);
  y = fmaf(y, x, 1.6666665459E-1f);
  y = fmaf(y, x, 5.0000001201E-1f);
  y = fmaf(y, z, x);
  y = y + 1.0f;
  return ldexpf(y, (int)fx);
}

__device__ __forceinline__ float log1p_x(float x) {
  float u = 1.0f + x;
  if (u == 1.0f) return x;
  return x * (log_x(u) / (u - 1.0f));
}

__device__ float erfinv_x(float x) {
  float w = -log1p_x(-(x * x));
  float p;
  if (w < 5.0f) {
    w = w - 2.5f;
    p = 2.81022636e-08f;
    p = p * w + 3.43273939e-07f;
    p = p * w + (-3.5233877e-06f);
    p = p * w + (-4.39150654e-06f);
    p = p * w + 0.00021858087f;
    p = p * w + (-0.00125372503f);
    p = p * w + (-0.00417768164f);
    p = p * w + 0.246640727f;
    p = p * w + 1.50140941f;
  } else {
    w = sqrtf(w) - 3.0f;
    p = -0.000200214257f;
    p = p * w + 0.000100950558f;
    p = p * w + 0.00134934322f;
    p = p * w + (-0.00367342844f);
    p = p * w + 0.00573950773f;
    p = p * w + (-0.0076224613f);
    p = p * w + 0.00943887047f;
    p = p * w + 1.00167406f;
    p = p * w + 2.83297682f;
  }
  return p * x;
}

#define F_NEG_ALMOST1 (-0.99999994039535522f)
#define F_SQRT2       (1.4142135623730951f)

#define NB   2048
#define NS   16
#define NV   64
#define ZDIM 320
#define SAMPLES_ELEMS (2048ull*16ull*320ull)
#define NSITES (2048u*16u*64u)         // 2,097,152
#define NROW   (2048u*64u)             // 131,072 km rows
#define CHUNK  256u                    // sites per wave
#define N_WAVES (NSITES / CHUNK)       // 8192 waves -> 2048 blocks of 256

// ===========================================================================
// Prep 1: per-row Wood constants {bw, aw, dw} -> ws (bit-identical formulas).
// ===========================================================================
__global__ __launch_bounds__(256) void prep_consts(const float* __restrict__ km,
                                                   float* __restrict__ ws) {
  uint32_t row = blockIdx.x * 256u + threadIdx.x;
  if (row >= NROW) return;
  const float* kp = km + (size_t)row * 5u;
  float m0 = kp[0], m1 = kp[1], m2 = kp[2], m3 = kp[3], m4 = kp[4];
  float kap = sqrtf(m0*m0 + m1*m1 + m2*m2 + m3*m3 + m4*m4);
  float cwv = sqrtf(4.0f * (kap * kap) + 16.0f);
  float b_true = (-2.0f * kap + cwv) / 4.0f;
  float b_app  = 4.0f / (4.0f * kap);
  float ssw = fminf(fmaxf(kap - 10.0f, 0.0f), 1.0f);
  float bw = b_app * ssw + b_true * (1.0f - ssw);
  float aw = (4.0f + 2.0f * kap + cwv) / 4.0f;
  float dw = (4.0f * aw * bw) / (1.0f + bw) - 5.545177444479562f;
  ws[row * 3u + 0u] = bw;
  ws[row * 3u + 1u] = aw;
  ws[row * 3u + 2u] = dw;
}

// ===========================================================================
// Prep 2: first-proposal gamma chain keys per site -> zo[1..4] (bitcast).
// These slots are scratch until vmf_finish overwrites them.
// ===========================================================================
__global__ __launch_bounds__(256) void prep_keys(float* __restrict__ out) {
  uint32_t site = blockIdx.x * 256u + threadIdx.x;   // 0..NSITES-1
  uint32_t i = site * 16u;
  U2 kA0 = srow(srow(KA, i), 0u);
  U2 kB0 = srow(srow(KB, i), 0u);
  uint32_t vv = site & (NV - 1u);
  uint32_t sb = site >> 6;
  uint32_t s  = sb >> 11;
  uint32_t b  = sb & (NB - 1u);
  float* zo = out + (size_t)(b * NS + s) * ZDIM + (size_t)vv * 5u;
  zo[1] = __uint_as_float(kA0.x);
  zo[2] = __uint_as_float(kA0.y);
  zo[3] = __uint_as_float(kB0.x);
  zo[4] = __uint_as_float(kB0.y);
}

// ===========================================================================
// Phase A: per-site w. Wave-local dynamic queue (256 sites/wave, no atomics).
// ===========================================================================
__global__ __launch_bounds__(256) void sample_w(const float* __restrict__ ws,
                                                float* __restrict__ out) {
  const int lane = threadIdx.x & 63;
  const uint32_t wave_id = blockIdx.x * 4u + (threadIdx.x >> 6);
  const uint32_t base = wave_id * CHUNK;

  const float Dg = 2.0f - 0.33333334f;
  const float Cg = 0.33333334f * (1.0f / sqrtf(Dg));       // 0.2581989 (r12)
  const float logDg = log_x(Dg);
  const unsigned long long lmask_lt = (1ull << lane) - 1ull;

  uint32_t next = 0;               // wave-uniform queue cursor
  bool need_site = true;
  bool lane_done = false;
  bool have = false;

  uint32_t site = 0, i = 0;
  int kprop = 0;
  bool phaseB = false;
  U2 k = {0u, 0u};
  U2 kB0 = {0u, 0u};               // stored first-proposal B chain key
  float bw = 0.f, aw = 0.f, dw = 0.f, w0 = 0.f, lga = 0.f;
  float* zo_cur = out;

  #pragma unroll 1
  for (int it = 0; it < 20000; ++it) {
    unsigned long long need = __ballot(need_site);
    if (need) {
      if (need_site) {
        uint32_t idx = next + (uint32_t)__popcll(need & lmask_lt);
        if (idx < CHUNK) {
          site = base + idx;
          uint32_t row = site & (NB * NV - 1u);   // b*NV+vv
          bw = ws[row * 3u + 0u];
          aw = ws[row * 3u + 1u];
          dw = ws[row * 3u + 2u];
          uint32_t vv = site & (NV - 1u);
          uint32_t sb = site >> 6;
          uint32_t s  = sb >> 11;
          uint32_t b  = sb & (NB - 1u);
          zo_cur = out + (size_t)(b * NS + s) * ZDIM + (size_t)vv * 5u;
          i = site * 16u;
          kprop = 0; phaseB = false;
          k.x = __float_as_uint(zo_cur[1]);       // precomputed kA0
          k.y = __float_as_uint(zo_cur[2]);
          kB0.x = __float_as_uint(zo_cur[3]);     // precomputed kB0
          kB0.y = __float_as_uint(zo_cur[4]);
          have = true;
        } else {
          lane_done = true;
          have = false;
        }
        need_site = false;
      }
      next += (uint32_t)__popcll(need);
    }
    if (__all(lane_done)) break;

    if (have) {
      // --- one MT trial with chain key k (bit-identical) ---
      U2 xk = srow(k, 1u);
      U2 Uk = srow(k, 2u);
      U2 sub = srow(xk, 1u);
      float f = u01f(rb(sub, 0u));
      float un = fmaxf(F_NEG_ALMOST1, f * 2.0f + F_NEG_ALMOST1);
      float x = F_SQRT2 * erfinv_x(un);
      float v = 1.0f + x * Cg;
      if (v <= 0.0f) {                    // rare inner redraw (x < -3.873)
        U2 chain = srow(xk, 0u);
        #pragma unroll 1
        for (int r = 0; r < 16 && v <= 0.0f; ++r) {
          U2 sk = srow(chain, 1u);
          chain = srow(chain, 0u);
          float f2 = u01f(rb(sk, 0u));
          float un2 = fmaxf(F_NEG_ALMOST1, f2 * 2.0f + F_NEG_ALMOST1);
          x = F_SQRT2 * erfinv_x(un2);
          v = 1.0f + x * Cg;
        }
      }
      float X = x * x;
      float V = (v * v) * v;
      float lV = log_x(V);
      float U = u01f(rb(Uk, 0u));
      bool c1 = U >= (1.0f - 0.0331f * (X * X));
      bool c2 = log_x(U) >= (X * 0.5f + Dg * ((1.0f - V) + lV));
      if (c1 && c2) {
        k = srow(k, 0u);                  // gamma rejected -> advance chain
      } else {
        float lg = logDg + lV;            // gamma accepted
        bool finish = false;
        float wres = 0.0f;
        if (!phaseB) {
          lga = lg;
          phaseB = true;
          k = (kprop == 0) ? kB0 : srow(srow(KB, i), 0u);
        } else {
          // --- Wood accept (single-exp form; exp_x(0)==1.0f exactly) ---
          float lgb = lg;
          bool age = (lga >= lgb);
          float dmin = (age ? lgb : lga) - (age ? lga : lgb);
          float eo = exp_x(dmin);
          float ea = age ? 1.0f : eo;
          float eb = age ? eo : 1.0f;
          float e = ea / (ea + eb);
          float fu = u01f(rb(T1, i));
          float uu = fmaxf(1e-20f, fu * 1.0f + 1e-20f);
          float denom = 1.0f - (1.0f - bw) * e;
          float wp = (1.0f - (1.0f + bw) * e) / denom;
          float tt = (2.0f * aw * bw) / denom;
          float st = 4.0f * log_x(tt) - tt + dw;
          bool acc = st > log_x(uu);
          if (kprop == 0) w0 = wp;
          if (acc) { wres = wp; finish = true; }
          else {
            ++kprop;
            if (kprop == 16) { wres = w0; finish = true; }
            else { ++i; phaseB = false; k = srow(srow(KA, i), 0u); }
          }
        }
        if (finish) {
          zo_cur[0] = wres;
          have = false;
          need_site = true;
        }
      }
    }
  }
}

// ===========================================================================
// Phase B: regular finish — read w, normals, Householder, logprob, reduce.
// ===========================================================================
__global__ __launch_bounds__(256) void vmf_finish(const float* __restrict__ km,
                                                  float* __restrict__ out) {
  const int tid  = threadIdx.x;
  const int wd   = tid >> 6;
  const int lane = tid & 63;
  const int bs   = blockIdx.x * 4 + wd;
  const int b    = bs >> 4;
  const int s    = bs & 15;
  const int vv   = lane;

  const float* kp = km + ((size_t)b * NV + vv) * 5;
  float m0 = kp[0], m1 = kp[1], m2 = kp[2], m3 = kp[3], m4 = kp[4];
  float kap = sqrtf(m0*m0 + m1*m1 + m2*m2 + m3*m3 + m4*m4);
  float l0 = m0 / (kap + 1e-5f);
  float l1 = m1 / (kap + 1e-5f);
  float l2 = m2 / (kap + 1e-5f);
  float l3 = m3 / (kap + 1e-5f);
  float l4 = m4 / (kap + 1e-5f);

  float* zo = out + (size_t)(b * NS + s) * ZDIM + (size_t)vv * 5;
  float w = zo[0];                               // stashed by phase A

  const uint32_t site = ((uint32_t)(s * NB + b) * NV + (uint32_t)vv);
  uint32_t j0 = site * 4u;
  float f, un, n0, n1, n2, n3;
  f = u01f(rb(T2, j0 + 0u)); un = fmaxf(F_NEG_ALMOST1, f*2.0f + F_NEG_ALMOST1); n0 = F_SQRT2*erfinv_x(un);
  f = u01f(rb(T2, j0 + 1u)); un = fmaxf(F_NEG_ALMOST1, f*2.0f + F_NEG_ALMOST1); n1 = F_SQRT2*erfinv_x(un);
  f = u01f(rb(T2, j0 + 2u)); un = fmaxf(F_NEG_ALMOST1, f*2.0f + F_NEG_ALMOST1); n2 = F_SQRT2*erfinv_x(un);
  f = u01f(rb(T2, j0 + 3u)); un = fmaxf(F_NEG_ALMOST1, f*2.0f + F_NEG_ALMOST1); n3 = F_SQRT2*erfinv_x(un);
  float nn = sqrtf(n0*n0 + n1*n1 + n2*n2 + n3*n3);
  n0 /= nn; n1 /= nn; n2 /= nn; n3 /= nn;

  float w_ = sqrtf(fmaxf(1.0f - w * w, 1e-10f));
  float x0 = w, x1 = w_ * n0, x2 = w_ * n1, x3 = w_ * n2, x4 = w_ * n3;

  float u0 = 1.0f - l0, u1 = -l1, u2 = -l2, u3 = -l3, u4 = -l4;
  float un_ = sqrtf(u0*u0 + u1*u1 + u2*u2 + u3*u3 + u4*u4);
  u0 /= (un_ + 1e-5f); u1 /= (un_ + 1e-5f); u2 /= (un_ + 1e-5f);
  u3 /= (un_ + 1e-5f); u4 /= (un_ + 1e-5f);
  float dot = x0*u0 + x1*u1 + x2*u2 + x3*u3 + x4*u4;
  float z0 = x0 - (2.0f * dot) * u0;
  float z1 = x1 - (2.0f * dot) * u1;
  float z2 = x2 - (2.0f * dot) * u2;
  float z3 = x3 - (2.0f * dot) * u3;
  float z4 = x4 - (2.0f * dot) * u4;

  zo[0] = z0; zo[1] = z1; zo[2] = z2; zo[3] = z3; zo[4] = z4;

  float dlz = l0*z0 + l1*z1 + l2*z2 + l3*z3 + l4*z4;
  float lu = dlz * kap;
  float em2 = exp_x(-2.0f * kap);
  float val = sqrtf(2.0f / (3.14159274f * kap)) *
              ((1.0f + em2) * 0.5f - (1.0f - em2) / (2.0f * kap));
  float li = log_x(val);
  float term = lu + ((1.5f * log_x(kap) - 4.594692666023363f) - (kap + li));

  float acc = term;
  #pragma unroll
  for (int off = 1; off < 64; off <<= 1) acc += __shfl_xor(acc, off, 64);
  if (lane == 0) out[SAMPLES_ELEMS + (size_t)(b * NS + s)] = acc;
}

extern "C" void kernel_launch(void* const* d_in, const int* in_sizes, int n_in,
                              void* d_out, int out_size, void* d_ws, size_t ws_size,
                              hipStream_t stream) {
  const float* km = (const float*)d_in[0];
  float* out = (float*)d_out;
  float* ws = (float*)d_ws;
  hipLaunchKernelGGL(prep_consts, dim3(NROW / 256),    dim3(256), 0, stream, km, ws);
  hipLaunchKernelGGL(prep_keys,   dim3(NSITES / 256),  dim3(256), 0, stream, out);
  hipLaunchKernelGGL(sample_w,    dim3(N_WAVES / 4),   dim3(256), 0, stream, ws, out);
  hipLaunchKernelGGL(vmf_finish,  dim3(32768 / 4),     dim3(256), 0, stream, km, out);
}

// Round 20
// 205.188 us; speedup vs baseline: 1.0195x; 1.0195x over previous
//
#include <hip/hip_runtime.h>
#include <stdint.h>
#include <math.h>

#pragma clang fp contract(off)

// ===========================================================================
// Threefry-2x32 (20 rounds) — constexpr so the wave-uniform key tree folds.
// Stream (CONFIRMED r11-r13): jax partitionable; split row i = tf(key,(0,i));
// 32-bit random_bits = x^y; root key(1) = (0,1); f32 draws.
// Gamma chain (CONFIRMED r13): ek=split(gkey)[i]; k=split2(ek)[0];
// loop{nk,xk,Uk=split3(k); sub=split2(xk)[1]}; MT c=(1/3)rsqrt(d).
// r19: fused prep (consts+keys, one launch); key table coalesced in d_ws when
// ws_size permits (host-checked), else proven out-slot fallback.
// ===========================================================================
struct U2 { uint32_t x, y; };

__host__ __device__ constexpr U2 tf(uint32_t k0, uint32_t k1, uint32_t x0, uint32_t x1) {
  uint32_t k2 = k0 ^ k1 ^ 0x1BD11BDAu;
#define TF_R(r) { x0 += x1; x1 = (x1 << (r)) | (x1 >> (32 - (r))); x1 ^= x0; }
  x0 += k0; x1 += k1;
  TF_R(13) TF_R(15) TF_R(26) TF_R(6)
  x0 += k1; x1 += k2 + 1u;
  TF_R(17) TF_R(29) TF_R(16) TF_R(24)
  x0 += k2; x1 += k0 + 2u;
  TF_R(13) TF_R(15) TF_R(26) TF_R(6)
  x0 += k0; x1 += k1 + 3u;
  TF_R(17) TF_R(29) TF_R(16) TF_R(24)
  x0 += k1; x1 += k2 + 4u;
  TF_R(13) TF_R(15) TF_R(26) TF_R(6)
  x0 += k2; x1 += k0 + 5u;
#undef TF_R
  return U2{x0, x1};
}

__device__ constexpr U2 T0 = tf(0u, 1u, 0u, 0u);
__device__ constexpr U2 T1 = tf(0u, 1u, 0u, 1u);
__device__ constexpr U2 T2 = tf(0u, 1u, 0u, 2u);
__device__ constexpr U2 KA = tf(T0.x, T0.y, 0u, 0u);
__device__ constexpr U2 KB = tf(T0.x, T0.y, 0u, 1u);

__device__ __forceinline__ U2 srow(U2 k, uint32_t i) { return tf(k.x, k.y, 0u, i); }
__device__ __forceinline__ uint32_t rb(U2 k, uint32_t i) {
  U2 r = tf(k.x, k.y, 0u, i); return r.x ^ r.y;
}

__device__ __forceinline__ float u01f(uint32_t b) {
  return __uint_as_float((b >> 9) | 0x3F800000u) - 1.0f;
}

// ===========================================================================
// f32 XLA Cephes math (bit-exact with reference; do not alter)
// ===========================================================================
__device__ float log_x(float a) {
  if (a == 0.0f) return -__builtin_inff();
  if (a < 0.0f) return __builtin_nanf("");
  if (__builtin_isinf(a)) return a;
  uint32_t bits = __float_as_uint(a);
  int e = (int)(bits >> 23) - 126;
  float m = __uint_as_float((bits & 0x007FFFFFu) | 0x3F000000u);
  if (m < 0.70710678118654752440f) { e -= 1; m = m + m - 1.0f; }
  else                             { m = m - 1.0f; }
  float z = m * m;
  float y = fmaf(7.0376836292E-2f, m, -1.1514610310E-1f);
  y = fmaf(y, m,  1.1676998740E-1f);
  y = fmaf(y, m, -1.2420140846E-1f);
  y = fmaf(y, m,  1.4249322787E-1f);
  y = fmaf(y, m, -1.6668057665E-1f);
  y = fmaf(y, m,  2.0000714765E-1f);
  y = fmaf(y, m, -2.4999993993E-1f);
  y = fmaf(y, m,  3.3333331174E-1f);
  y = y * m; y = y * z;
  y = fmaf((float)e, -2.12194440e-4f, y);
  y = fmaf(z, -0.5f, y);
  float r = m + y;
  r = fmaf((float)e, 0.693359375f, r);
  return r;
}

__device__ float exp_x(float a) {
  float x = fminf(a, 88.3762626647950f);
  x = fmaxf(x, -88.3762626647949f);
  float fx = floorf(fmaf(x, 1.44269504088896341f, 0.5f));
  x = x - fx * 0.693359375f;
  x = x - fx * (-2.12194440e-4f);
  float z = x * x;
  float y = fmaf(1.9875691500E-4f, x, 1.3981999507E-3f);
  y = fmaf(y, x, 8.3334519073E-3f);
  y = fmaf(y, x, 4.1665795894E-2f);
  y = fmaf(y, x, 1.6666665459E-1f);
  y = fmaf(y, x, 5.0000001201E-1f);
  y = fmaf(y, z, x);
  y = y + 1.0f;
  return ldexpf(y, (int)fx);
}

__device__ __forceinline__ float log1p_x(float x) {
  float u = 1.0f + x;
  if (u == 1.0f) return x;
  return x * (log_x(u) / (u - 1.0f));
}

__device__ float erfinv_x(float x) {
  float w = -log1p_x(-(x * x));
  float p;
  if (w < 5.0f) {
    w = w - 2.5f;
    p = 2.81022636e-08f;
    p = p * w + 3.43273939e-07f;
    p = p * w + (-3.5233877e-06f);
    p = p * w + (-4.39150654e-06f);
    p = p * w + 0.00021858087f;
    p = p * w + (-0.00125372503f);
    p = p * w + (-0.00417768164f);
    p = p * w + 0.246640727f;
    p = p * w + 1.50140941f;
  } else {
    w = sqrtf(w) - 3.0f;
    p = -0.000200214257f;
    p = p * w + 0.000100950558f;
    p = p * w + 0.00134934322f;
    p = p * w + (-0.00367342844f);
    p = p * w + 0.00573950773f;
    p = p * w + (-0.0076224613f);
    p = p * w + 0.00943887047f;
    p = p * w + 1.00167406f;
    p = p * w + 2.83297682f;
  }
  return p * x;
}

#define F_NEG_ALMOST1 (-0.99999994039535522f)
#define F_SQRT2       (1.4142135623730951f)

#define NB   2048
#define NS   16
#define NV   64
#define ZDIM 320
#define SAMPLES_ELEMS (2048ull*16ull*320ull)
#define NSITES (2048u*16u*64u)         // 2,097,152
#define NROW   (2048u*64u)             // 131,072 km rows
#define CHUNK  256u                    // sites per wave
#define N_WAVES (NSITES / CHUNK)       // 8192 waves -> 2048 blocks of 256
#define KEY_OFF (NROW * 3u)            // float offset of key table in ws
#define WS_FLOATS_NEEDED (KEY_OFF + NSITES * 4u)   // ~8.78M floats = 33.5MB

// ===========================================================================
// Fused prep: consts (first NROW threads) + first-proposal chain keys.
// use_ws: 1 -> keys coalesced in ws[KEY_OFF + site*4]; 0 -> out zo[1..4].
// ===========================================================================
__global__ __launch_bounds__(256) void prep_fused(const float* __restrict__ km,
                                                  float* __restrict__ ws,
                                                  float* __restrict__ out,
                                                  int use_ws) {
  uint32_t site = blockIdx.x * 256u + threadIdx.x;   // 0..NSITES-1
  if (site < NROW) {
    const float* kp = km + (size_t)site * 5u;
    float m0 = kp[0], m1 = kp[1], m2 = kp[2], m3 = kp[3], m4 = kp[4];
    float kap = sqrtf(m0*m0 + m1*m1 + m2*m2 + m3*m3 + m4*m4);
    float cwv = sqrtf(4.0f * (kap * kap) + 16.0f);
    float b_true = (-2.0f * kap + cwv) / 4.0f;
    float b_app  = 4.0f / (4.0f * kap);
    float ssw = fminf(fmaxf(kap - 10.0f, 0.0f), 1.0f);
    float bw = b_app * ssw + b_true * (1.0f - ssw);
    float aw = (4.0f + 2.0f * kap + cwv) / 4.0f;
    float dw = (4.0f * aw * bw) / (1.0f + bw) - 5.545177444479562f;
    ws[site * 3u + 0u] = bw;
    ws[site * 3u + 1u] = aw;
    ws[site * 3u + 2u] = dw;
  }
  uint32_t i = site * 16u;
  U2 kA0 = srow(srow(KA, i), 0u);
  U2 kB0 = srow(srow(KB, i), 0u);
  if (use_ws) {
    float* kt = ws + KEY_OFF + (size_t)site * 4u;
    kt[0] = __uint_as_float(kA0.x);
    kt[1] = __uint_as_float(kA0.y);
    kt[2] = __uint_as_float(kB0.x);
    kt[3] = __uint_as_float(kB0.y);
  } else {
    uint32_t vv = site & (NV - 1u);
    uint32_t sb = site >> 6;
    uint32_t s  = sb >> 11;
    uint32_t b  = sb & (NB - 1u);
    float* zo = out + (size_t)(b * NS + s) * ZDIM + (size_t)vv * 5u;
    zo[1] = __uint_as_float(kA0.x);
    zo[2] = __uint_as_float(kA0.y);
    zo[3] = __uint_as_float(kB0.x);
    zo[4] = __uint_as_float(kB0.y);
  }
}

// ===========================================================================
// Phase A: per-site w. Wave-local dynamic queue (256 sites/wave, no atomics).
// ===========================================================================
__global__ __launch_bounds__(256) void sample_w(const float* __restrict__ ws,
                                                float* __restrict__ out,
                                                int use_ws) {
  const int lane = threadIdx.x & 63;
  const uint32_t wave_id = blockIdx.x * 4u + (threadIdx.x >> 6);
  const uint32_t base = wave_id * CHUNK;

  const float Dg = 2.0f - 0.33333334f;
  const float Cg = 0.33333334f * (1.0f / sqrtf(Dg));       // 0.2581989 (r12)
  const float logDg = log_x(Dg);
  const unsigned long long lmask_lt = (1ull << lane) - 1ull;

  uint32_t next = 0;               // wave-uniform queue cursor
  bool need_site = true;
  bool lane_done = false;
  bool have = false;

  uint32_t site = 0, i = 0;
  int kprop = 0;
  bool phaseB = false;
  U2 k = {0u, 0u};
  U2 kB0 = {0u, 0u};
  float bw = 0.f, aw = 0.f, dw = 0.f, w0 = 0.f, lga = 0.f;
  float* zo_cur = out;

  #pragma unroll 1
  for (int it = 0; it < 20000; ++it) {
    unsigned long long need = __ballot(need_site);
    if (need) {
      if (need_site) {
        uint32_t idx = next + (uint32_t)__popcll(need & lmask_lt);
        if (idx < CHUNK) {
          site = base + idx;
          uint32_t row = site & (NB * NV - 1u);   // b*NV+vv
          bw = ws[row * 3u + 0u];
          aw = ws[row * 3u + 1u];
          dw = ws[row * 3u + 2u];
          uint32_t vv = site & (NV - 1u);
          uint32_t sb = site >> 6;
          uint32_t s  = sb >> 11;
          uint32_t b  = sb & (NB - 1u);
          zo_cur = out + (size_t)(b * NS + s) * ZDIM + (size_t)vv * 5u;
          i = site * 16u;
          kprop = 0; phaseB = false;
          if (use_ws) {
            const float* kt = ws + KEY_OFF + (size_t)site * 4u;
            k.x   = __float_as_uint(kt[0]);
            k.y   = __float_as_uint(kt[1]);
            kB0.x = __float_as_uint(kt[2]);
            kB0.y = __float_as_uint(kt[3]);
          } else {
            k.x   = __float_as_uint(zo_cur[1]);
            k.y   = __float_as_uint(zo_cur[2]);
            kB0.x = __float_as_uint(zo_cur[3]);
            kB0.y = __float_as_uint(zo_cur[4]);
          }
          have = true;
        } else {
          lane_done = true;
          have = false;
        }
        need_site = false;
      }
      next += (uint32_t)__popcll(need);
    }
    if (__all(lane_done)) break;

    if (have) {
      // --- one MT trial with chain key k (bit-identical) ---
      U2 xk = srow(k, 1u);
      U2 Uk = srow(k, 2u);
      U2 sub = srow(xk, 1u);
      float f = u01f(rb(sub, 0u));
      float un = fmaxf(F_NEG_ALMOST1, f * 2.0f + F_NEG_ALMOST1);
      float x = F_SQRT2 * erfinv_x(un);
      float v = 1.0f + x * Cg;
      if (v <= 0.0f) {                    // rare inner redraw (x < -3.873)
        U2 chain = srow(xk, 0u);
        #pragma unroll 1
        for (int r = 0; r < 16 && v <= 0.0f; ++r) {
          U2 sk = srow(chain, 1u);
          chain = srow(chain, 0u);
          float f2 = u01f(rb(sk, 0u));
          float un2 = fmaxf(F_NEG_ALMOST1, f2 * 2.0f + F_NEG_ALMOST1);
          x = F_SQRT2 * erfinv_x(un2);
          v = 1.0f + x * Cg;
        }
      }
      float X = x * x;
      float V = (v * v) * v;
      float lV = log_x(V);
      float U = u01f(rb(Uk, 0u));
      bool c1 = U >= (1.0f - 0.0331f * (X * X));
      bool c2 = log_x(U) >= (X * 0.5f + Dg * ((1.0f - V) + lV));
      if (c1 && c2) {
        k = srow(k, 0u);                  // gamma rejected -> advance chain
      } else {
        float lg = logDg + lV;            // gamma accepted
        bool finish = false;
        float wres = 0.0f;
        if (!phaseB) {
          lga = lg;
          phaseB = true;
          k = (kprop == 0) ? kB0 : srow(srow(KB, i), 0u);
        } else {
          // --- Wood accept (single-exp form; exp_x(0)==1.0f exactly) ---
          float lgb = lg;
          bool age = (lga >= lgb);
          float dmin = (age ? lgb : lga) - (age ? lga : lgb);
          float eo = exp_x(dmin);
          float ea = age ? 1.0f : eo;
          float eb = age ? eo : 1.0f;
          float e = ea / (ea + eb);
          float fu = u01f(rb(T1, i));
          float uu = fmaxf(1e-20f, fu * 1.0f + 1e-20f);
          float denom = 1.0f - (1.0f - bw) * e;
          float wp = (1.0f - (1.0f + bw) * e) / denom;
          float tt = (2.0f * aw * bw) / denom;
          float st = 4.0f * log_x(tt) - tt + dw;
          bool acc = st > log_x(uu);
          if (kprop == 0) w0 = wp;
          if (acc) { wres = wp; finish = true; }
          else {
            ++kprop;
            if (kprop == 16) { wres = w0; finish = true; }
            else { ++i; phaseB = false; k = srow(srow(KA, i), 0u); }
          }
        }
        if (finish) {
          zo_cur[0] = wres;
          have = false;
          need_site = true;
        }
      }
    }
  }
}

// ===========================================================================
// Phase B: regular finish — read w, normals, Householder, logprob, reduce.
// ===========================================================================
__global__ __launch_bounds__(256) void vmf_finish(const float* __restrict__ km,
                                                  float* __restrict__ out) {
  const int tid  = threadIdx.x;
  const int wd   = tid >> 6;
  const int lane = tid & 63;
  const int bs   = blockIdx.x * 4 + wd;
  const int b    = bs >> 4;
  const int s    = bs & 15;
  const int vv   = lane;

  const float* kp = km + ((size_t)b * NV + vv) * 5;
  float m0 = kp[0], m1 = kp[1], m2 = kp[2], m3 = kp[3], m4 = kp[4];
  float kap = sqrtf(m0*m0 + m1*m1 + m2*m2 + m3*m3 + m4*m4);
  float l0 = m0 / (kap + 1e-5f);
  float l1 = m1 / (kap + 1e-5f);
  float l2 = m2 / (kap + 1e-5f);
  float l3 = m3 / (kap + 1e-5f);
  float l4 = m4 / (kap + 1e-5f);

  float* zo = out + (size_t)(b * NS + s) * ZDIM + (size_t)vv * 5;
  float w = zo[0];                               // stashed by phase A

  const uint32_t site = ((uint32_t)(s * NB + b) * NV + (uint32_t)vv);
  uint32_t j0 = site * 4u;
  float f, un, n0, n1, n2, n3;
  f = u01f(rb(T2, j0 + 0u)); un = fmaxf(F_NEG_ALMOST1, f*2.0f + F_NEG_ALMOST1); n0 = F_SQRT2*erfinv_x(un);
  f = u01f(rb(T2, j0 + 1u)); un = fmaxf(F_NEG_ALMOST1, f*2.0f + F_NEG_ALMOST1); n1 = F_SQRT2*erfinv_x(un);
  f = u01f(rb(T2, j0 + 2u)); un = fmaxf(F_NEG_ALMOST1, f*2.0f + F_NEG_ALMOST1); n2 = F_SQRT2*erfinv_x(un);
  f = u01f(rb(T2, j0 + 3u)); un = fmaxf(F_NEG_ALMOST1, f*2.0f + F_NEG_ALMOST1); n3 = F_SQRT2*erfinv_x(un);
  float nn = sqrtf(n0*n0 + n1*n1 + n2*n2 + n3*n3);
  n0 /= nn; n1 /= nn; n2 /= nn; n3 /= nn;

  float w_ = sqrtf(fmaxf(1.0f - w * w, 1e-10f));
  float x0 = w, x1 = w_ * n0, x2 = w_ * n1, x3 = w_ * n2, x4 = w_ * n3;

  float u0 = 1.0f - l0, u1 = -l1, u2 = -l2, u3 = -l3, u4 = -l4;
  float un_ = sqrtf(u0*u0 + u1*u1 + u2*u2 + u3*u3 + u4*u4);
  u0 /= (un_ + 1e-5f); u1 /= (un_ + 1e-5f); u2 /= (un_ + 1e-5f);
  u3 /= (un_ + 1e-5f); u4 /= (un_ + 1e-5f);
  float dot = x0*u0 + x1*u1 + x2*u2 + x3*u3 + x4*u4;
  float z0 = x0 - (2.0f * dot) * u0;
  float z1 = x1 - (2.0f * dot) * u1;
  float z2 = x2 - (2.0f * dot) * u2;
  float z3 = x3 - (2.0f * dot) * u3;
  float z4 = x4 - (2.0f * dot) * u4;

  zo[0] = z0; zo[1] = z1; zo[2] = z2; zo[3] = z3; zo[4] = z4;

  float dlz = l0*z0 + l1*z1 + l2*z2 + l3*z3 + l4*z4;
  float lu = dlz * kap;
  float em2 = exp_x(-2.0f * kap);
  float val = sqrtf(2.0f / (3.14159274f * kap)) *
              ((1.0f + em2) * 0.5f - (1.0f - em2) / (2.0f * kap));
  float li = log_x(val);
  float term = lu + ((1.5f * log_x(kap) - 4.594692666023363f) - (kap + li));

  float acc = term;
  #pragma unroll
  for (int off = 1; off < 64; off <<= 1) acc += __shfl_xor(acc, off, 64);
  if (lane == 0) out[SAMPLES_ELEMS + (size_t)(b * NS + s)] = acc;
}

extern "C" void kernel_launch(void* const* d_in, const int* in_sizes, int n_in,
                              void* d_out, int out_size, void* d_ws, size_t ws_size,
                              hipStream_t stream) {
  const float* km = (const float*)d_in[0];
  float* out = (float*)d_out;
  float* ws = (float*)d_ws;
  int use_ws = (ws_size >= (size_t)WS_FLOATS_NEEDED * 4u) ? 1 : 0;
  hipLaunchKernelGGL(prep_fused, dim3(NSITES / 256), dim3(256), 0, stream, km, ws, out, use_ws);
  hipLaunchKernelGGL(sample_w,   dim3(N_WAVES / 4),  dim3(256), 0, stream, ws, out, use_ws);
  hipLaunchKernelGGL(vmf_finish, dim3(32768 / 4),    dim3(256), 0, stream, km, out);
}

// Round 21
// 204.488 us; speedup vs baseline: 1.0230x; 1.0034x over previous
//
#include <hip/hip_runtime.h>
#include <stdint.h>
#include <math.h>

#pragma clang fp contract(off)

// ===========================================================================
// Threefry-2x32 (20 rounds) — constexpr so the wave-uniform key tree folds.
// Stream (CONFIRMED r11-r13): jax partitionable; split row i = tf(key,(0,i));
// 32-bit random_bits = x^y; root key(1) = (0,1); f32 draws.
// Gamma chain (CONFIRMED r13): ek=split(gkey)[i]; k=split2(ek)[0];
// loop{nk,xk,Uk=split3(k); sub=split2(xk)[1]}; MT c=(1/3)rsqrt(d).
// r20: finish fused into sample_w — wave's 256-site chunk = 4 (b,s) pairs;
// w via wave-local LDS; one launch + one global round-trip removed.
// ===========================================================================
struct U2 { uint32_t x, y; };

__host__ __device__ constexpr U2 tf(uint32_t k0, uint32_t k1, uint32_t x0, uint32_t x1) {
  uint32_t k2 = k0 ^ k1 ^ 0x1BD11BDAu;
#define TF_R(r) { x0 += x1; x1 = (x1 << (r)) | (x1 >> (32 - (r))); x1 ^= x0; }
  x0 += k0; x1 += k1;
  TF_R(13) TF_R(15) TF_R(26) TF_R(6)
  x0 += k1; x1 += k2 + 1u;
  TF_R(17) TF_R(29) TF_R(16) TF_R(24)
  x0 += k2; x1 += k0 + 2u;
  TF_R(13) TF_R(15) TF_R(26) TF_R(6)
  x0 += k0; x1 += k1 + 3u;
  TF_R(17) TF_R(29) TF_R(16) TF_R(24)
  x0 += k1; x1 += k2 + 4u;
  TF_R(13) TF_R(15) TF_R(26) TF_R(6)
  x0 += k2; x1 += k0 + 5u;
#undef TF_R
  return U2{x0, x1};
}

__device__ constexpr U2 T0 = tf(0u, 1u, 0u, 0u);
__device__ constexpr U2 T1 = tf(0u, 1u, 0u, 1u);
__device__ constexpr U2 T2 = tf(0u, 1u, 0u, 2u);
__device__ constexpr U2 KA = tf(T0.x, T0.y, 0u, 0u);
__device__ constexpr U2 KB = tf(T0.x, T0.y, 0u, 1u);

__device__ __forceinline__ U2 srow(U2 k, uint32_t i) { return tf(k.x, k.y, 0u, i); }
__device__ __forceinline__ uint32_t rb(U2 k, uint32_t i) {
  U2 r = tf(k.x, k.y, 0u, i); return r.x ^ r.y;
}

__device__ __forceinline__ float u01f(uint32_t b) {
  return __uint_as_float((b >> 9) | 0x3F800000u) - 1.0f;
}

// ===========================================================================
// f32 XLA Cephes math (bit-exact with reference; do not alter)
// ===========================================================================
__device__ float log_x(float a) {
  if (a == 0.0f) return -__builtin_inff();
  if (a < 0.0f) return __builtin_nanf("");
  if (__builtin_isinf(a)) return a;
  uint32_t bits = __float_as_uint(a);
  int e = (int)(bits >> 23) - 126;
  float m = __uint_as_float((bits & 0x007FFFFFu) | 0x3F000000u);
  if (m < 0.70710678118654752440f) { e -= 1; m = m + m - 1.0f; }
  else                             { m = m - 1.0f; }
  float z = m * m;
  float y = fmaf(7.0376836292E-2f, m, -1.1514610310E-1f);
  y = fmaf(y, m,  1.1676998740E-1f);
  y = fmaf(y, m, -1.2420140846E-1f);
  y = fmaf(y, m,  1.4249322787E-1f);
  y = fmaf(y, m, -1.6668057665E-1f);
  y = fmaf(y, m,  2.0000714765E-1f);
  y = fmaf(y, m, -2.4999993993E-1f);
  y = fmaf(y, m,  3.3333331174E-1f);
  y = y * m; y = y * z;
  y = fmaf((float)e, -2.12194440e-4f, y);
  y = fmaf(z, -0.5f, y);
  float r = m + y;
  r = fmaf((float)e, 0.693359375f, r);
  return r;
}

__device__ float exp_x(float a) {
  float x = fminf(a, 88.3762626647950f);
  x = fmaxf(x, -88.3762626647949f);
  float fx = floorf(fmaf(x, 1.44269504088896341f, 0.5f));
  x = x - fx * 0.693359375f;
  x = x - fx * (-2.12194440e-4f);
  float z = x * x;
  float y = fmaf(1.9875691500E-4f, x, 1.3981999507E-3f);
  y = fmaf(y, x, 8.3334519073E-3f);
  y = fmaf(y, x, 4.1665795894E-2f);
  y = fmaf(y, x, 1.6666665459E-1f);
  y = fmaf(y, x, 5.0000001201E-1f);
  y = fmaf(y, z, x);
  y = y + 1.0f;
  return ldexpf(y, (int)fx);
}

__device__ __forceinline__ float log1p_x(float x) {
  float u = 1.0f + x;
  if (u == 1.0f) return x;
  return x * (log_x(u) / (u - 1.0f));
}

__device__ float erfinv_x(float x) {
  float w = -log1p_x(-(x * x));
  float p;
  if (w < 5.0f) {
    w = w - 2.5f;
    p = 2.81022636e-08f;
    p = p * w + 3.43273939e-07f;
    p = p * w + (-3.5233877e-06f);
    p = p * w + (-4.39150654e-06f);
    p = p * w + 0.00021858087f;
    p = p * w + (-0.00125372503f);
    p = p * w + (-0.00417768164f);
    p = p * w + 0.246640727f;
    p = p * w + 1.50140941f;
  } else {
    w = sqrtf(w) - 3.0f;
    p = -0.000200214257f;
    p = p * w + 0.000100950558f;
    p = p * w + 0.00134934322f;
    p = p * w + (-0.00367342844f);
    p = p * w + 0.00573950773f;
    p = p * w + (-0.0076224613f);
    p = p * w + 0.00943887047f;
    p = p * w + 1.00167406f;
    p = p * w + 2.83297682f;
  }
  return p * x;
}

#define F_NEG_ALMOST1 (-0.99999994039535522f)
#define F_SQRT2       (1.4142135623730951f)

#define NB   2048
#define NS   16
#define NV   64
#define ZDIM 320
#define SAMPLES_ELEMS (2048ull*16ull*320ull)
#define NSITES (2048u*16u*64u)         // 2,097,152
#define NROW   (2048u*64u)             // 131,072 km rows
#define CHUNK  256u                    // sites per wave = 4 (b,s) pairs
#define N_WAVES (NSITES / CHUNK)       // 8192 waves -> 2048 blocks of 256
#define KEY_OFF (NROW * 3u)            // float offset of key table in ws
#define WS_FLOATS_NEEDED (KEY_OFF + NSITES * 4u)   // ~8.78M floats = 33.5MB

// ===========================================================================
// Fused prep: consts (first NROW threads) + first-proposal chain keys.
// ===========================================================================
__global__ __launch_bounds__(256) void prep_fused(const float* __restrict__ km,
                                                  float* __restrict__ ws,
                                                  float* __restrict__ out,
                                                  int use_ws) {
  uint32_t site = blockIdx.x * 256u + threadIdx.x;   // 0..NSITES-1
  if (site < NROW) {
    const float* kp = km + (size_t)site * 5u;
    float m0 = kp[0], m1 = kp[1], m2 = kp[2], m3 = kp[3], m4 = kp[4];
    float kap = sqrtf(m0*m0 + m1*m1 + m2*m2 + m3*m3 + m4*m4);
    float cwv = sqrtf(4.0f * (kap * kap) + 16.0f);
    float b_true = (-2.0f * kap + cwv) / 4.0f;
    float b_app  = 4.0f / (4.0f * kap);
    float ssw = fminf(fmaxf(kap - 10.0f, 0.0f), 1.0f);
    float bw = b_app * ssw + b_true * (1.0f - ssw);
    float aw = (4.0f + 2.0f * kap + cwv) / 4.0f;
    float dw = (4.0f * aw * bw) / (1.0f + bw) - 5.545177444479562f;
    ws[site * 3u + 0u] = bw;
    ws[site * 3u + 1u] = aw;
    ws[site * 3u + 2u] = dw;
  }
  uint32_t i = site * 16u;
  U2 kA0 = srow(srow(KA, i), 0u);
  U2 kB0 = srow(srow(KB, i), 0u);
  if (use_ws) {
    float* kt = ws + KEY_OFF + (size_t)site * 4u;
    kt[0] = __uint_as_float(kA0.x);
    kt[1] = __uint_as_float(kA0.y);
    kt[2] = __uint_as_float(kB0.x);
    kt[3] = __uint_as_float(kB0.y);
  } else {
    uint32_t vv = site & (NV - 1u);
    uint32_t sb = site >> 6;
    uint32_t s  = sb >> 11;
    uint32_t b  = sb & (NB - 1u);
    float* zo = out + (size_t)(b * NS + s) * ZDIM + (size_t)vv * 5u;
    zo[1] = __uint_as_float(kA0.x);
    zo[2] = __uint_as_float(kA0.y);
    zo[3] = __uint_as_float(kB0.x);
    zo[4] = __uint_as_float(kB0.y);
  }
}

// ===========================================================================
// Fused phase A+B: wave-local queue over 256 sites (w -> LDS), then the wave
// runs the finish math for its own 4 (b,s) pairs.
// ===========================================================================
__global__ __launch_bounds__(256) void vmf_fused(const float* __restrict__ km,
                                                 const float* __restrict__ ws,
                                                 float* __restrict__ out,
                                                 int use_ws) {
  __shared__ float ldsW[4][CHUNK];
  const int lane = threadIdx.x & 63;
  const int wd   = threadIdx.x >> 6;
  const uint32_t wave_id = blockIdx.x * 4u + (uint32_t)wd;
  const uint32_t base = wave_id * CHUNK;

  const float Dg = 2.0f - 0.33333334f;
  const float Cg = 0.33333334f * (1.0f / sqrtf(Dg));       // 0.2581989 (r12)
  const float logDg = log_x(Dg);
  const unsigned long long lmask_lt = (1ull << lane) - 1ull;

  uint32_t next = 0;               // wave-uniform queue cursor
  bool need_site = true;
  bool lane_done = false;
  bool have = false;

  uint32_t site = 0, i = 0, idx_cur = 0;
  int kprop = 0;
  bool phaseB = false;
  U2 k = {0u, 0u};
  U2 kB0 = {0u, 0u};
  float bw = 0.f, aw = 0.f, dw = 0.f, w0 = 0.f, lga = 0.f;
  const float* kslots = out;       // fallback key slots base (read-only here)

  #pragma unroll 1
  for (int it = 0; it < 20000; ++it) {
    unsigned long long need = __ballot(need_site);
    if (need) {
      if (need_site) {
        uint32_t idx = next + (uint32_t)__popcll(need & lmask_lt);
        if (idx < CHUNK) {
          site = base + idx;
          idx_cur = idx;
          uint32_t row = site & (NB * NV - 1u);   // b*NV+vv
          bw = ws[row * 3u + 0u];
          aw = ws[row * 3u + 1u];
          dw = ws[row * 3u + 2u];
          i = site * 16u;
          kprop = 0; phaseB = false;
          if (use_ws) {
            const float* kt = ws + KEY_OFF + (size_t)site * 4u;
            k.x   = __float_as_uint(kt[0]);
            k.y   = __float_as_uint(kt[1]);
            kB0.x = __float_as_uint(kt[2]);
            kB0.y = __float_as_uint(kt[3]);
          } else {
            uint32_t vv = site & (NV - 1u);
            uint32_t sb = site >> 6;
            uint32_t s  = sb >> 11;
            uint32_t b  = sb & (NB - 1u);
            const float* zo = kslots + (size_t)(b * NS + s) * ZDIM + (size_t)vv * 5u;
            k.x   = __float_as_uint(zo[1]);
            k.y   = __float_as_uint(zo[2]);
            kB0.x = __float_as_uint(zo[3]);
            kB0.y = __float_as_uint(zo[4]);
          }
          have = true;
        } else {
          lane_done = true;
          have = false;
        }
        need_site = false;
      }
      next += (uint32_t)__popcll(need);
    }
    if (__all(lane_done)) break;

    if (have) {
      // --- one MT trial with chain key k (bit-identical) ---
      U2 xk = srow(k, 1u);
      U2 Uk = srow(k, 2u);
      U2 sub = srow(xk, 1u);
      float f = u01f(rb(sub, 0u));
      float un = fmaxf(F_NEG_ALMOST1, f * 2.0f + F_NEG_ALMOST1);
      float x = F_SQRT2 * erfinv_x(un);
      float v = 1.0f + x * Cg;
      if (v <= 0.0f) {                    // rare inner redraw (x < -3.873)
        U2 chain = srow(xk, 0u);
        #pragma unroll 1
        for (int r = 0; r < 16 && v <= 0.0f; ++r) {
          U2 sk = srow(chain, 1u);
          chain = srow(chain, 0u);
          float f2 = u01f(rb(sk, 0u));
          float un2 = fmaxf(F_NEG_ALMOST1, f2 * 2.0f + F_NEG_ALMOST1);
          x = F_SQRT2 * erfinv_x(un2);
          v = 1.0f + x * Cg;
        }
      }
      float X = x * x;
      float V = (v * v) * v;
      float lV = log_x(V);
      float U = u01f(rb(Uk, 0u));
      bool c1 = U >= (1.0f - 0.0331f * (X * X));
      bool c2 = log_x(U) >= (X * 0.5f + Dg * ((1.0f - V) + lV));
      if (c1 && c2) {
        k = srow(k, 0u);                  // gamma rejected -> advance chain
      } else {
        float lg = logDg + lV;            // gamma accepted
        bool finish = false;
        float wres = 0.0f;
        if (!phaseB) {
          lga = lg;
          phaseB = true;
          k = (kprop == 0) ? kB0 : srow(srow(KB, i), 0u);
        } else {
          // --- Wood accept (single-exp form; exp_x(0)==1.0f exactly) ---
          float lgb = lg;
          bool age = (lga >= lgb);
          float dmin = (age ? lgb : lga) - (age ? lga : lgb);
          float eo = exp_x(dmin);
          float ea = age ? 1.0f : eo;
          float eb = age ? eo : 1.0f;
          float e = ea / (ea + eb);
          float fu = u01f(rb(T1, i));
          float uu = fmaxf(1e-20f, fu * 1.0f + 1e-20f);
          float denom = 1.0f - (1.0f - bw) * e;
          float wp = (1.0f - (1.0f + bw) * e) / denom;
          float tt = (2.0f * aw * bw) / denom;
          float st = 4.0f * log_x(tt) - tt + dw;
          bool acc = st > log_x(uu);
          if (kprop == 0) w0 = wp;
          if (acc) { wres = wp; finish = true; }
          else {
            ++kprop;
            if (kprop == 16) { wres = w0; finish = true; }
            else { ++i; phaseB = false; k = srow(srow(KA, i), 0u); }
          }
        }
        if (finish) {
          ldsW[wd][idx_cur] = wres;       // wave-local stash
          have = false;
          need_site = true;
        }
      }
    }
  }

  // ===== finish: this wave's 4 (b,s) pairs (bit-identical to vmf_finish) ===
  #pragma unroll 1
  for (int q = 0; q < 4; ++q) {
    uint32_t sb = wave_id * 4u + (uint32_t)q;
    uint32_t s  = sb >> 11;
    uint32_t b  = sb & (NB - 1u);
    int vv = lane;

    const float* kp = km + ((size_t)b * NV + vv) * 5;
    float m0 = kp[0], m1 = kp[1], m2 = kp[2], m3 = kp[3], m4 = kp[4];
    float kap = sqrtf(m0*m0 + m1*m1 + m2*m2 + m3*m3 + m4*m4);
    float l0 = m0 / (kap + 1e-5f);
    float l1 = m1 / (kap + 1e-5f);
    float l2 = m2 / (kap + 1e-5f);
    float l3 = m3 / (kap + 1e-5f);
    float l4 = m4 / (kap + 1e-5f);

    float w = ldsW[wd][q * 64 + lane];

    const uint32_t site_f = sb * NV + (uint32_t)vv;
    uint32_t j0 = site_f * 4u;
    float f, un, n0, n1, n2, n3;
    f = u01f(rb(T2, j0 + 0u)); un = fmaxf(F_NEG_ALMOST1, f*2.0f + F_NEG_ALMOST1); n0 = F_SQRT2*erfinv_x(un);
    f = u01f(rb(T2, j0 + 1u)); un = fmaxf(F_NEG_ALMOST1, f*2.0f + F_NEG_ALMOST1); n1 = F_SQRT2*erfinv_x(un);
    f = u01f(rb(T2, j0 + 2u)); un = fmaxf(F_NEG_ALMOST1, f*2.0f + F_NEG_ALMOST1); n2 = F_SQRT2*erfinv_x(un);
    f = u01f(rb(T2, j0 + 3u)); un = fmaxf(F_NEG_ALMOST1, f*2.0f + F_NEG_ALMOST1); n3 = F_SQRT2*erfinv_x(un);
    float nn = sqrtf(n0*n0 + n1*n1 + n2*n2 + n3*n3);
    n0 /= nn; n1 /= nn; n2 /= nn; n3 /= nn;

    float w_ = sqrtf(fmaxf(1.0f - w * w, 1e-10f));
    float x0 = w, x1 = w_ * n0, x2 = w_ * n1, x3 = w_ * n2, x4 = w_ * n3;

    float u0 = 1.0f - l0, u1 = -l1, u2 = -l2, u3 = -l3, u4 = -l4;
    float un_ = sqrtf(u0*u0 + u1*u1 + u2*u2 + u3*u3 + u4*u4);
    u0 /= (un_ + 1e-5f); u1 /= (un_ + 1e-5f); u2 /= (un_ + 1e-5f);
    u3 /= (un_ + 1e-5f); u4 /= (un_ + 1e-5f);
    float dot = x0*u0 + x1*u1 + x2*u2 + x3*u3 + x4*u4;
    float z0 = x0 - (2.0f * dot) * u0;
    float z1 = x1 - (2.0f * dot) * u1;
    float z2 = x2 - (2.0f * dot) * u2;
    float z3 = x3 - (2.0f * dot) * u3;
    float z4 = x4 - (2.0f * dot) * u4;

    float* zo = out + (size_t)(b * NS + s) * ZDIM + (size_t)vv * 5;
    zo[0] = z0; zo[1] = z1; zo[2] = z2; zo[3] = z3; zo[4] = z4;

    float dlz = l0*z0 + l1*z1 + l2*z2 + l3*z3 + l4*z4;
    float lu = dlz * kap;
    float em2 = exp_x(-2.0f * kap);
    float val = sqrtf(2.0f / (3.14159274f * kap)) *
                ((1.0f + em2) * 0.5f - (1.0f - em2) / (2.0f * kap));
    float li = log_x(val);
    float term = lu + ((1.5f * log_x(kap) - 4.594692666023363f) - (kap + li));

    float acc = term;
    #pragma unroll
    for (int off = 1; off < 64; off <<= 1) acc += __shfl_xor(acc, off, 64);
    if (lane == 0) out[SAMPLES_ELEMS + (size_t)(b * NS + s)] = acc;
  }
}

extern "C" void kernel_launch(void* const* d_in, const int* in_sizes, int n_in,
                              void* d_out, int out_size, void* d_ws, size_t ws_size,
                              hipStream_t stream) {
  const float* km = (const float*)d_in[0];
  float* out = (float*)d_out;
  float* ws = (float*)d_ws;
  int use_ws = (ws_size >= (size_t)WS_FLOATS_NEEDED * 4u) ? 1 : 0;
  hipLaunchKernelGGL(prep_fused, dim3(NSITES / 256), dim3(256), 0, stream, km, ws, out, use_ws);
  hipLaunchKernelGGL(vmf_fused,  dim3(N_WAVES / 4),  dim3(256), 0, stream, km, ws, out, use_ws);
}